// Round 8
// baseline (137.246 us; speedup 1.0000x reference)
//
#include <hip/hip_runtime.h>

// SSM DPLR kernel: K[h,l] = 2*Re(C_h . dA_h^l . dB_h), dA = diag(g) + q r^T.
// R7: l = 64i+j, dual chain over M2 = dA^128 (R6 structure), but ALL serial
// scalar phases replaced by parallel ones:
//   u = (1-zW)^{-1} mod z^128 via Newton doubling (seed u8, 4 stages)
//   sigma = u*a, tau = w*u  (parallel convolutions)
//   T64/T128/T' via block contractions A1,A1d,A2,A2d against the G-table
//   X rebuilt 8 rows/wave via block scan
// Rolled loops throughout to keep instruction footprint small (R6's 12MB
// FETCH_SIZE was instruction streaming).

#define LL 2048

struct C2 { float re, im; };

__device__ __forceinline__ C2 cmul(C2 a, C2 b){ return {a.re*b.re - a.im*b.im, a.re*b.im + a.im*b.re}; }
__device__ __forceinline__ C2 cadd(C2 a, C2 b){ return {a.re+b.re, a.im+b.im}; }
__device__ __forceinline__ C2 csub(C2 a, C2 b){ return {a.re-b.re, a.im-b.im}; }
__device__ __forceinline__ C2 cinv(C2 a){ float s=1.0f/(a.re*a.re+a.im*a.im); return {a.re*s, -a.im*s}; }
__device__ __forceinline__ C2 cscale(float s, C2 a){ return {s*a.re, s*a.im}; }
__device__ __forceinline__ C2 ld2(float2 v){ return {v.x, v.y}; }
__device__ __forceinline__ float2 st2(C2 v){ return make_float2(v.re, v.im); }

template<int CTRL>
__device__ __forceinline__ float dpp_add(float x){
  int t = __builtin_amdgcn_update_dpp(0, __float_as_int(x), CTRL, 0xF, 0xF, true);
  return x + __int_as_float(t);
}
__device__ __forceinline__ float wave_sum63(float x){
  x = dpp_add<0xB1>(x); x = dpp_add<0x4E>(x); x = dpp_add<0x124>(x);
  x = dpp_add<0x128>(x); x = dpp_add<0x142>(x); x = dpp_add<0x143>(x);
  return x;
}
__device__ __forceinline__ float bcast63(float x){
  return __int_as_float(__builtin_amdgcn_readlane(__float_as_int(x), 63));
}
__device__ __forceinline__ float rdl(float v, int l){
  return __int_as_float(__builtin_amdgcn_readlane(__float_as_int(v), l));
}
__device__ __forceinline__ C2 rdl2(C2 v, int l){ return { rdl(v.re, l), rdl(v.im, l) }; }
__device__ __forceinline__ float shr1(float x){
  return __int_as_float(__builtin_amdgcn_update_dpp(0, __float_as_int(x), 0x138, 0xF, 0xF, true));
}

__global__ __launch_bounds__(512) void ssm_dplr_kernel(
    const float* __restrict__ A_real, const float* __restrict__ A_imag,
    const float* __restrict__ B_real, const float* __restrict__ B_imag,
    const float* __restrict__ P_real, const float* __restrict__ P_imag,
    const float* __restrict__ C_real, const float* __restrict__ C_imag,
    const float* __restrict__ log_dt, float* __restrict__ out)
{
    const int h    = blockIdx.x;
    const int t    = threadIdx.x;
    const int lane = t & 63;
    const int widu = __builtin_amdgcn_readfirstlane(t >> 6);   // 0..7

    extern __shared__ char sm[];
    float2* Xbuf = (float2*)sm;              // 32KB: G table, then X rows
    float2* Cs   = (float2*)(sm + 32768);    // 16KB: a-partials, then C_i rows
    float2* prt  = (float2*)(sm + 49152);    // 8KB: partials / tA / tauA / sgA / chain
    float2* wA   = (float2*)(sm + 57344);    // 128: w_l, l<128
    float2* uA   = (float2*)(sm + 58368);    // 128: Newton u
    float2* aA   = (float2*)(sm + 59392);    // 64:  a_j
    float2* A1A  = (float2*)(sm + 59904);    // 64 each:
    float2* A1dA = A1A + 64;
    float2* A2A  = A1A + 128;
    float2* A2dA = A1A + 192;
    float2* tA   = prt;                      // Newton temp   [0:128)
    float2* tauA = prt + 128;                // tau           [128:256)
    float2* sgA  = prt + 256;                // sigma         [256:320)

    // ---------------- setup ----------------
    const int idx = h * 64 + lane;
    const float dt = expf(log_dt[h]);
    const float c  = 0.5f * dt;

    const C2 lam = { -A_real[idx], -A_imag[idx] };
    const C2 p   = {  P_real[idx],  P_imag[idx] };
    const C2 Bv  = {  B_real[idx],  B_imag[idx] };
    const C2 Cv  = {  C_real[idx],  C_imag[idx] };
    const C2 pc  = { p.re, -p.im };

    const C2 d = cinv(C2{ 1.0f - c*lam.re, -c*lam.im });
    const C2 g = cmul(d, C2{ 1.0f + c*lam.re, c*lam.im });

    C2 sv = cscale(p.re*p.re + p.im*p.im, d);
    C2 uv = cmul(cmul(d, pc), Bv);
    sv.re = bcast63(wave_sum63(sv.re)); sv.im = bcast63(wave_sum63(sv.im));
    uv.re = bcast63(wave_sum63(uv.re)); uv.im = bcast63(wave_sum63(uv.im));

    const C2 beta  = cscale(c, cinv(C2{ 1.0f + c*sv.re, c*sv.im }));
    const C2 bs    = cmul(beta, sv);
    const C2 gamma = { -c*(1.0f - bs.re), c*bs.im };

    const C2 q  = cmul(d, p);
    const C2 r  = cmul(pc, csub(gamma, cmul(beta, g)));
    const C2 x0 = cscale(dt, csub(cmul(d, Bv), cmul(cmul(beta, uv), q)));  // dB
    const C2 rq  = cmul(r, q);
    const C2 rx  = cmul(r, x0);

    const C2 g2   = cmul(g,  g);
    const C2 g4   = cmul(g2, g2);
    const C2 g8   = cmul(g4, g4);
    const C2 g16  = cmul(g8, g8);
    const C2 g32  = cmul(g16,g16);
    const C2 g64  = cmul(g32,g32);
    const C2 g128 = cmul(g64,g64);
    const C2 rqg  = cmul(rq, g64);

    // ---------------- G table: G[j][n] = g_n^j (rotated cols), j in [8w,8w+8) ----------------
    {
        C2 cur = {1.0f, 0.0f};
        if (widu & 1) cur = g8;
        if (widu & 2) cur = cmul(cur, g16);
        if (widu & 4) cur = cmul(cur, g32);
        for (int jj = 0; jj < 8; ++jj) {
            const int j = 8*widu + jj;
            Xbuf[j*64 + ((lane + j) & 63)] = st2(cur);
            cur = cmul(cur, g);
        }
    }
    __syncthreads();   // B1

    // ---------------- partials: w_j, w_{64+j}, a_j (lane = j) ----------------
    {
        C2 accw = {0,0}, accv = {0,0}, acca = {0,0};
        for (int kk = 0; kk < 8; ++kk) {
            const int n = 8*widu + kk;
            const C2 Gv = ld2(Xbuf[lane*64 + ((n + lane) & 63)]);
            accw = cadd(accw, cmul(Gv, rdl2(rq,  n)));
            accv = cadd(accv, cmul(Gv, rdl2(rqg, n)));
            acca = cadd(acca, cmul(Gv, rdl2(rx,  n)));
        }
        prt[widu*64 + lane]       = st2(accw);
        prt[512 + widu*64 + lane] = st2(accv);
        Cs[widu*64 + lane]        = st2(acca);
    }
    __syncthreads();   // B2

    // ---------------- reduce + u seed ----------------
    if (widu == 0) {
        C2 wl = {0,0};
        for (int w2 = 0; w2 < 8; ++w2) {
            const float2 v = prt[w2*64 + lane];
            wl.re += v.x; wl.im += v.y;
        }
        wA[lane] = st2(wl);
        // u seed: u_0 = 1; u_l = sum_{i<l} w_{l-1-i} u_i, 8 systolic steps
        C2 va = {0,0};
        if (lane == 0) va.re = 1.0f;
        C2 wsh = { shr1(wl.re), shr1(wl.im) };
        C2 so = {0,0};
        for (int j = 0; j < 8; ++j) {
            const float sr = rdl(va.re, j), si = rdl(va.im, j);
            if (lane == j) { so.re = sr; so.im = si; }
            va.re += wsh.re*sr - wsh.im*si;
            va.im += wsh.re*si + wsh.im*sr;
            wsh.re = shr1(wsh.re); wsh.im = shr1(wsh.im);
        }
        if (lane < 8) uA[lane] = st2(so);
    } else if (widu == 1) {
        C2 wl = {0,0};
        for (int w2 = 0; w2 < 8; ++w2) {
            const float2 v = prt[512 + w2*64 + lane];
            wl.re += v.x; wl.im += v.y;
        }
        wA[64 + lane] = st2(wl);
    } else if (widu == 2) {
        C2 al = {0,0};
        for (int w2 = 0; w2 < 8; ++w2) {
            const float2 v = Cs[w2*64 + lane];
            al.re += v.x; al.im += v.y;
        }
        aA[lane] = st2(al);
    }
    __syncthreads();   // B3

    // ---------------- Newton: u -> 16 -> 32 -> 64 -> 128 ----------------
    for (int m = 8; m < 128; m <<= 1) {
        const int M2s = 2*m;
        if (t < M2s) {
            C2 acc = (t < m) ? ld2(uA[t]) : C2{0.0f, 0.0f};
            const int ib = (t < m) ? t : m;
            for (int i = 0; i < ib; ++i)
                acc = csub(acc, cmul(ld2(wA[t-1-i]), ld2(uA[i])));
            tA[t] = st2(acc);
        }
        __syncthreads();
        if (t >= m && t < M2s) {
            C2 acc = {0,0};
            for (int j = 0; j < m; ++j)
                acc = csub(acc, cmul(ld2(uA[j]), ld2(tA[t-j])));
            uA[t] = st2(acc);
        }
        __syncthreads();
    }   // B4..B11

    // ---------------- sigma = u*a (l<64), tau = w*u (i<127) ----------------
    if (t < 64) {
        C2 acc = {0,0};
        for (int j = 0; j <= t; ++j)
            acc = cadd(acc, cmul(ld2(aA[j]), ld2(uA[t-j])));
        sgA[t] = st2(acc);
    } else if (t < 191) {
        const int i = t - 64;
        C2 acc = {0,0};
        for (int k = 0; k <= i; ++k)
            acc = cadd(acc, cmul(ld2(wA[i-k]), ld2(uA[k])));
        tauA[i] = st2(acc);
    }
    __syncthreads();   // B12

    // ---------------- A-block contractions (T64 = A1, T64' = A1d,
    //                   T128 = g64*A1 + A2, T128' = 64 g63 A1 + g64 A1d + A2d) ----------------
    if (widu == 0) {
        C2 A1 = {0,0}, A1d = {0,0};
        float jp1 = 1.0f;
        for (int j = 0; j <= 63; ++j) {
            const C2 Gj = ld2(Xbuf[j*64 + ((lane + j) & 63)]);
            if (j >= 1)  A1  = cadd(A1,  cmul(ld2(tauA[63-j]), Gj));
            if (j <= 62) A1d = cadd(A1d, cscale(jp1, cmul(ld2(tauA[62-j]), Gj)));
            jp1 += 1.0f;
        }
        A1A[lane]  = st2(A1);
        A1dA[lane] = st2(A1d);
    } else if (widu == 1) {
        C2 A2 = {0,0}, A2d = {0,0};
        float jp1 = 1.0f;
        for (int j = 0; j <= 63; ++j) {
            const C2 Gj = ld2(Xbuf[j*64 + ((lane + j) & 63)]);
            if (j >= 1) A2 = cadd(A2, cmul(ld2(tauA[127-j]), Gj));
            A2d = cadd(A2d, cscale(jp1, cmul(ld2(tauA[126-j]), Gj)));
            jp1 += 1.0f;
        }
        A2 = cadd(A2, cmul(ld2(tauA[63]), g64));   // j = 64 term
        A2A[lane]  = st2(A2);
        A2dA[lane] = st2(A2d);
    }
    __syncthreads();   // B13

    // ---------------- X build: wave w writes rows j in [8w, 8w+8) ----------------
    {
        C2 pw[8]; pw[0] = {1.0f, 0.0f};
        for (int k = 1; k < 8; ++k) pw[k] = cmul(pw[k-1], g);
        C2 e = {0,0};
        for (int b = 0; b < widu; ++b) {
            C2 ph = {0,0};
            for (int i = 0; i < 8; ++i)
                ph = cadd(ph, cmul(pw[7-i], ld2(sgA[8*b + i])));
            e = cadd(cmul(g8, e), ph);
        }
        C2 gp = {1.0f, 0.0f};
        if (widu & 1) gp = g8;
        if (widu & 2) gp = cmul(gp, g16);
        if (widu & 4) gp = cmul(gp, g32);
        for (int m = 0; m < 8; ++m) {
            const int j = 8*widu + m;
            const C2 X = cadd(cmul(gp, x0), cmul(q, e));
            Xbuf[j*64 + ((lane + j) & 63)] = st2(X);
            e  = cadd(cmul(g, e), ld2(sgA[j]));
            gp = cmul(g, gp);
        }
    }
    __syncthreads();   // B14

    // ---------------- T values (regs) + M2 rows + seed M64 ----------------
    const C2 A1m  = ld2(A1A[lane]),  A1dm = ld2(A1dA[lane]);
    const C2 A2m  = ld2(A2A[lane]),  A2dm = ld2(A2dA[lane]);
    const C2 Tg128m = cadd(cmul(g64, A1m), A2m);

    C2 M2k[16];
    {
        #pragma unroll
        for (int k = 0; k < 16; ++k) {
            const int n = 16*(widu & 3) + k;
            const C2 gn    = rdl2(g,      n);
            const C2 qn    = rdl2(q,      n);
            const C2 g128n = rdl2(g128,   n);
            const C2 Tgn   = rdl2(Tg128m, n);
            const C2 idm   = cinv(csub(gn, g));
            const C2 num   = cmul(r, cadd(csub(g128n, g128), csub(Tgn, Tg128m)));
            M2k[k] = cmul(cmul(qn, num), idm);
        }
        if ((lane >> 4) == (widu & 3)) {
            const int k0 = lane & 15;
            const C2 ginv = cinv(g);
            const C2 g127 = cmul(g128, ginv);
            const C2 g63  = cmul(g64,  ginv);
            const C2 Tp128 = cadd(cadd(cscale(64.0f, cmul(g63, A1m)), cmul(g64, A1dm)), A2dm);
            const C2 S = cmul(r, cadd(cscale(128.0f, g127), Tp128));
            M2k[k0] = cadd(g128, cmul(q, S));
        }
    }

    if (widu >= 4) {      // seed C1 = C0 * M64 (T64 = A1, T64' = A1d)
        C2 Mk64[16];
        #pragma unroll
        for (int k = 0; k < 16; ++k) {
            const int n = 16*(widu - 4) + k;
            const C2 gn   = rdl2(g,   n);
            const C2 qn   = rdl2(q,   n);
            const C2 g64n = rdl2(g64, n);
            const C2 Tgn  = rdl2(A1m, n);
            const C2 idm  = cinv(csub(gn, g));
            const C2 num  = cmul(r, cadd(csub(g64n, g64), csub(Tgn, A1m)));
            Mk64[k] = cmul(cmul(qn, num), idm);
        }
        if ((lane >> 4) == (widu - 4)) {
            const int k0 = lane & 15;
            const C2 g63 = cmul(g64, cinv(g));
            const C2 S   = cmul(r, cadd(cscale(64.0f, g63), A1dm));
            Mk64[k0] = cadd(g64, cmul(q, S));
        }
        C2 acc = {0,0};
        #pragma unroll
        for (int k = 0; k < 16; ++k) {
            const int n = 16*(widu - 4) + k;
            const float cr  = rdl(Cv.re, n);
            const float cim = rdl(Cv.im, n);
            acc.re += cr*Mk64[k].re - cim*Mk64[k].im;
            acc.im += cr*Mk64[k].im + cim*Mk64[k].re;
        }
        prt[512 + widu*64 + lane] = st2(acc);
    }
    __syncthreads();   // B15

    C2 Cc;
    if (widu < 4) {
        Cc = Cv;                                 // C_0
    } else {
        const float2 p4 = prt[512 + 256 + lane], p5 = prt[512 + 320 + lane];
        const float2 p6 = prt[512 + 384 + lane], p7 = prt[512 + 448 + lane];
        Cc.re = (p4.x + p5.x) + (p6.x + p7.x);
        Cc.im = (p4.y + p5.y) + (p6.y + p7.y);   // C_1
    }

    // ---------------- dual chain: C_{i+2} = C_i M2, 15 barrier iters ----------------
    for (int a = 0; a < 16; ++a) {
        if (widu == 0) Cs[(2*a)*64 + lane]   = st2(Cc);
        if (widu == 4) Cs[(2*a+1)*64 + lane] = st2(Cc);
        if (a == 15) break;
        C2 acc = {0,0};
        #pragma unroll
        for (int k = 0; k < 16; ++k) {
            const int n = 16*(widu & 3) + k;
            const float cr  = rdl(Cc.re, n);
            const float cim = rdl(Cc.im, n);
            acc.re += cr*M2k[k].re - cim*M2k[k].im;
            acc.im += cr*M2k[k].im + cim*M2k[k].re;
        }
        float2* buf = prt + (a & 1)*512;
        buf[widu*64 + lane] = st2(acc);
        __syncthreads();
        const int base = (widu < 4) ? 0 : 256;
        const float2 p0 = buf[base + lane],       p1 = buf[base + 64 + lane];
        const float2 p2 = buf[base + 128 + lane], p3 = buf[base + 192 + lane];
        Cc.re = (p0.x + p1.x) + (p2.x + p3.x);
        Cc.im = (p0.y + p1.y) + (p2.y + p3.y);
    }
    __syncthreads();   // B16

    // ---------------- output: K[64i+j] = 2 Re( sum_n C_i[n] X_j[n] ) ----------------
    {
        const int j = lane;
        C2 Csr[4];
        #pragma unroll
        for (int rr = 0; rr < 4; ++rr) Csr[rr] = ld2(Cs[(4*widu + rr)*64 + lane]);
        float accK[4] = {0,0,0,0};
        #pragma unroll 8
        for (int n = 0; n < 64; ++n) {
            const float2 xv = Xbuf[j*64 + ((n + j) & 63)];
            #pragma unroll
            for (int rr = 0; rr < 4; ++rr)
                accK[rr] += rdl(Csr[rr].re, n)*xv.x - rdl(Csr[rr].im, n)*xv.y;
        }
        float* outh = out + h * LL;
        #pragma unroll
        for (int rr = 0; rr < 4; ++rr)
            outh[(4*widu + rr)*64 + j] = 2.0f * accK[rr];
    }
}

extern "C" void kernel_launch(void* const* d_in, const int* in_sizes, int n_in,
                              void* d_out, int out_size, void* d_ws, size_t ws_size,
                              hipStream_t stream) {
    const float* A_real = (const float*)d_in[0];
    const float* A_imag = (const float*)d_in[1];
    const float* B_real = (const float*)d_in[2];
    const float* B_imag = (const float*)d_in[3];
    const float* P_real = (const float*)d_in[4];
    const float* P_imag = (const float*)d_in[5];
    const float* C_real = (const float*)d_in[6];
    const float* C_imag = (const float*)d_in[7];
    const float* log_dt = (const float*)d_in[8];
    float* out = (float*)d_out;

    const size_t lds = 61952;
    ssm_dplr_kernel<<<256, 512, lds, stream>>>(
        A_real, A_imag, B_real, B_imag, P_real, P_imag,
        C_real, C_imag, log_dt, out);
}

// Round 9
// 125.261 us; speedup vs baseline: 1.0957x; 1.0957x over previous
//
#include <hip/hip_runtime.h>

// SSM DPLR kernel: K[h,l] = 2*Re(C_h . dA_h^l . dB_h), dA = diag(g) + q r^T.
// R8 = R5 + __launch_bounds__(512, 2).
// R5/R6/R7 counters showed VGPR_Count 32 for kernels with >=50 live values and
// WRITE_SIZE 5-13x the output: the default occupancy heuristic was spilling to
// scratch (HBM-backed). 8-wave block needs only 2 waves/EU -> grant the
// allocator the full 256-VGPR budget explicitly.

#define LL 2048

struct C2 { float re, im; };

__device__ __forceinline__ C2 cmul(C2 a, C2 b){ return {a.re*b.re - a.im*b.im, a.re*b.im + a.im*b.re}; }
__device__ __forceinline__ C2 cadd(C2 a, C2 b){ return {a.re+b.re, a.im+b.im}; }
__device__ __forceinline__ C2 csub(C2 a, C2 b){ return {a.re-b.re, a.im-b.im}; }
__device__ __forceinline__ C2 cinv(C2 a){ float s=1.0f/(a.re*a.re+a.im*a.im); return {a.re*s, -a.im*s}; }
__device__ __forceinline__ C2 cscale(float s, C2 a){ return {s*a.re, s*a.im}; }
__device__ __forceinline__ C2 ld2(float2 v){ return {v.x, v.y}; }
__device__ __forceinline__ float2 st2(C2 v){ return make_float2(v.re, v.im); }

template<int CTRL>
__device__ __forceinline__ float dpp_add(float x){
  int t = __builtin_amdgcn_update_dpp(0, __float_as_int(x), CTRL, 0xF, 0xF, true);
  return x + __int_as_float(t);
}
__device__ __forceinline__ float wave_sum63(float x){
  x = dpp_add<0xB1>(x);   // quad_perm xor1
  x = dpp_add<0x4E>(x);   // quad_perm xor2
  x = dpp_add<0x124>(x);  // row_ror:4
  x = dpp_add<0x128>(x);  // row_ror:8
  x = dpp_add<0x142>(x);  // row_bcast:15
  x = dpp_add<0x143>(x);  // row_bcast:31
  return x;
}
__device__ __forceinline__ float bcast63(float x){
  return __int_as_float(__builtin_amdgcn_readlane(__float_as_int(x), 63));
}
__device__ __forceinline__ float rdl(float v, int l){
  return __int_as_float(__builtin_amdgcn_readlane(__float_as_int(v), l));
}
__device__ __forceinline__ C2 rdl2(C2 v, int l){
  return { rdl(v.re, l), rdl(v.im, l) };
}
// lane i <- lane i-1, lane0 <- 0   (wave_shr:1)
__device__ __forceinline__ float shr1(float x){
  return __int_as_float(__builtin_amdgcn_update_dpp(0, __float_as_int(x), 0x138, 0xF, 0xF, true));
}

__global__ __launch_bounds__(512, 2) void ssm_dplr_kernel(
    const float* __restrict__ A_real, const float* __restrict__ A_imag,
    const float* __restrict__ B_real, const float* __restrict__ B_imag,
    const float* __restrict__ P_real, const float* __restrict__ P_imag,
    const float* __restrict__ C_real, const float* __restrict__ C_imag,
    const float* __restrict__ log_dt, float* __restrict__ out)
{
    const int h    = blockIdx.x;
    const int t    = threadIdx.x;
    const int lane = t & 63;
    const int widu = __builtin_amdgcn_readfirstlane(t >> 6);   // SGPR wave id 0..7

    extern __shared__ char sm[];
    float2* Abuf = (float2*)sm;              // 64x64: G powers, later X   [32 KB]
    float2* Cs   = (float2*)(sm + 32768);    // 32x64 C_i rows             [16 KB]
    float2* prt  = (float2*)(sm + 49152);    // 2 x 512 partials           [ 8 KB]
    float2* TgA  = (float2*)(sm + 57344);    // 64
    float2* TpA  = TgA + 64;                 // 64

    // ---------------- setup (every wave, per-lane n = lane) ----------------
    const int idx = h * 64 + lane;
    const float dt = expf(log_dt[h]);
    const float c  = 0.5f * dt;

    const C2 lam = { -A_real[idx], -A_imag[idx] };
    const C2 p   = {  P_real[idx],  P_imag[idx] };
    const C2 Bv  = {  B_real[idx],  B_imag[idx] };
    const C2 Cv  = {  C_real[idx],  C_imag[idx] };
    const C2 pc  = { p.re, -p.im };

    const C2 d = cinv(C2{ 1.0f - c*lam.re, -c*lam.im });
    const C2 g = cmul(d, C2{ 1.0f + c*lam.re, c*lam.im });   // diag of dA

    C2 sv = cscale(p.re*p.re + p.im*p.im, d);
    C2 uv = cmul(cmul(d, pc), Bv);
    sv.re = bcast63(wave_sum63(sv.re)); sv.im = bcast63(wave_sum63(sv.im));
    uv.re = bcast63(wave_sum63(uv.re)); uv.im = bcast63(wave_sum63(uv.im));

    const C2 beta  = cscale(c, cinv(C2{ 1.0f + c*sv.re, c*sv.im }));
    const C2 bs    = cmul(beta, sv);
    const C2 gamma = { -c*(1.0f - bs.re), c*bs.im };

    const C2 q  = cmul(d, p);
    const C2 r  = cmul(pc, csub(gamma, cmul(beta, g)));
    const C2 x0 = cscale(dt, csub(cmul(d, Bv), cmul(cmul(beta, uv), q)));  // dB
    const C2 rq = cmul(r, q);
    const C2 rx = cmul(r, x0);

    const C2 g2  = cmul(g,  g);
    const C2 g4  = cmul(g2, g2);
    const C2 g8  = cmul(g4, g4);
    const C2 g16 = cmul(g8, g8);
    const C2 g32 = cmul(g16,g16);
    const C2 g64 = cmul(g32,g32);

    // ---------------- G-gen: G[j][n] = g_n^j, rows j in [8w, 8w+8) ----------------
    {
        C2 cur = {1.0f, 0.0f};
        if (widu & 1) cur = g8;
        if (widu & 2) cur = cmul(cur, g16);
        if (widu & 4) cur = cmul(cur, g32);
        #pragma unroll
        for (int jj = 0; jj < 8; ++jj) {
            const int j = 8*widu + jj;
            Abuf[j*64 + ((lane + j) & 63)] = st2(cur);   // rotated columns
            cur = cmul(cur, g);
        }
    }
    __syncthreads();   // B1

    // ---------------- w_j, a_j partials (lane = j), broadcasts via readlane ----------------
    {
        C2 accw = {0,0}, acca = {0,0};
        #pragma unroll
        for (int kk = 0; kk < 8; ++kk) {
            const int n = 8*widu + kk;
            const C2 Gv = ld2(Abuf[lane*64 + ((n + lane) & 63)]);
            const C2 fq = rdl2(rq, n);
            const C2 fx = rdl2(rx, n);
            accw = cadd(accw, cmul(Gv, fq));
            acca = cadd(acca, cmul(Gv, fx));
        }
        prt[widu*64 + lane]       = st2(accw);
        prt[512 + widu*64 + lane] = st2(acca);
    }
    __syncthreads();   // B2

    // ---------------- solves (waves 0,1) + dependent solo phases ----------------
    C2 so = {0.0f, 0.0f};     // wave0: sigma_lane; wave1: tau_lane
    if (widu < 2) {
        // reduce w (both waves need the kernel), a only for wave0
        C2 wl = {0,0};
        {
            const float2 w0 = prt[lane],       w1 = prt[64+lane],  w2 = prt[128+lane], w3 = prt[192+lane];
            const float2 w4 = prt[256+lane],   w5 = prt[320+lane], w6 = prt[384+lane], w7 = prt[448+lane];
            wl.re = ((w0.x+w1.x)+(w2.x+w3.x)) + ((w4.x+w5.x)+(w6.x+w7.x));
            wl.im = ((w0.y+w1.y)+(w2.y+w3.y)) + ((w4.y+w5.y)+(w6.y+w7.y));
        }
        C2 va;
        if (widu == 0) {
            const float2 a0 = prt[512+lane],     a1 = prt[512+64+lane],  a2 = prt[512+128+lane], a3 = prt[512+192+lane];
            const float2 a4 = prt[512+256+lane], a5 = prt[512+320+lane], a6 = prt[512+384+lane], a7 = prt[512+448+lane];
            va.re = ((a0.x+a1.x)+(a2.x+a3.x)) + ((a4.x+a5.x)+(a6.x+a7.x));
            va.im = ((a0.y+a1.y)+(a2.y+a3.y)) + ((a4.y+a5.y)+(a6.y+a7.y));
        } else {
            va = wl;
        }
        // triangular-Toeplitz solve: v_j = rhs_j + sum_{i<j} w_{j-1-i} v_i
        C2 wsh = { shr1(wl.re), shr1(wl.im) };
        for (int j = 0; j < 64; ++j) {
            const float sr = rdl(va.re, j);
            const float si = rdl(va.im, j);
            if (lane == j) { so.re = sr; so.im = si; }
            va.re += wsh.re*sr - wsh.im*si;
            va.im += wsh.re*si + wsh.im*sr;
            wsh.re = shr1(wsh.re);
            wsh.im = shr1(wsh.im);
        }
    }
    if (widu == 0) {
        // X rebuild from own sigma registers: X_{j+1} = g.*X_j + sigma_j q
        C2 x = x0;
        for (int j = 0; j < 64; ++j) {
            Abuf[j*64 + ((lane + j) & 63)] = st2(x);
            const float sjr = rdl(so.re, j);
            const float sji = rdl(so.im, j);
            const float nr = g.re*x.re - g.im*x.im + sjr*q.re - sji*q.im;
            const float ni = g.re*x.im + g.im*x.re + sjr*q.im + sji*q.re;
            x.re = nr; x.im = ni;
        }
    } else if (widu == 1) {
        // T(z) = z * P(z), P from tau (own registers); T' = P + z P'
        C2 pp = rdl2(so, 0);
        C2 dd = {0,0};
        for (int i = 1; i <= 62; ++i) {
            const C2 ti = rdl2(so, i);
            const C2 nd = cadd(cmul(dd, g), pp);
            pp = cadd(cmul(pp, g), ti);
            dd = nd;
        }
        TgA[lane] = st2(cmul(g, pp));
        TpA[lane] = st2(cadd(pp, cmul(g, dd)));
    }
    __syncthreads();   // B3

    // ---------------- M build: Mk[k] = M[8w+k][lane] ----------------
    // M[n][m] = d_{nm} g64_n + q_n r_m [ (g64_n-g64_m) + (T(g_n)-T(g_m)) ] / (g_n-g_m)
    // M[n][n] = g64_n + q_n r_n ( 64 g_n^63 + T'(g_n) )
    C2 Mk[8];
    {
        const C2 Tgm = ld2(TgA[lane]);
        #pragma unroll
        for (int k = 0; k < 8; ++k) {
            const int n = 8*widu + k;
            const C2 gn   = rdl2(g,   n);
            const C2 qn   = rdl2(q,   n);
            const C2 g64n = rdl2(g64, n);
            const C2 Tgn  = rdl2(Tgm, n);
            const C2 idm  = cinv(csub(gn, g));     // inf on n==lane, overwritten below
            const C2 num  = cmul(r, cadd(csub(g64n, g64), csub(Tgn, Tgm)));
            Mk[k] = cmul(cmul(qn, num), idm);
        }
        if ((lane >> 3) == widu) {
            const int k0 = lane & 7;
            const C2 Tp  = ld2(TpA[lane]);
            const C2 g63 = cmul(g64, cinv(g));
            const C2 S   = cmul(r, cadd(cscale(64.0f, g63), Tp));
            Mk[k0] = cadd(g64, cmul(q, S));
        }
    }

    // ---------------- C chain: C_{i+1} = C_i M ----------------
    C2 Ci = Cv;
    for (int i = 0; i < 32; ++i) {
        if (widu == 0) Cs[i*64 + lane] = st2(Ci);
        if (i == 31) break;
        C2 acc = {0,0};
        #pragma unroll
        for (int k = 0; k < 8; ++k) {
            const float cr  = rdl(Ci.re, 8*widu + k);
            const float cim = rdl(Ci.im, 8*widu + k);
            acc.re += cr*Mk[k].re - cim*Mk[k].im;
            acc.im += cr*Mk[k].im + cim*Mk[k].re;
        }
        float2* buf = prt + (i & 1)*512;
        buf[widu*64 + lane] = st2(acc);
        __syncthreads();
        const float2 p0 = buf[lane],     p1 = buf[64+lane],  p2 = buf[128+lane], p3 = buf[192+lane];
        const float2 p4 = buf[256+lane], p5 = buf[320+lane], p6 = buf[384+lane], p7 = buf[448+lane];
        Ci.re = ((p0.x+p1.x)+(p2.x+p3.x)) + ((p4.x+p5.x)+(p6.x+p7.x));
        Ci.im = ((p0.y+p1.y)+(p2.y+p3.y)) + ((p4.y+p5.y)+(p6.y+p7.y));
    }
    __syncthreads();   // B4

    // ---------------- output: K[64i+j] = 2 Re( sum_n C_i[n] X_j[n] ), i in [4w,4w+4) ----------------
    {
        const int j = lane;
        C2 Csr[4];
        #pragma unroll
        for (int rr = 0; rr < 4; ++rr) Csr[rr] = ld2(Cs[(4*widu + rr)*64 + lane]);
        float accK[4] = {0,0,0,0};
        #pragma unroll 8
        for (int n = 0; n < 64; ++n) {
            const float2 xv = Abuf[j*64 + ((n + j) & 63)];
            #pragma unroll
            for (int rr = 0; rr < 4; ++rr) {
                accK[rr] += rdl(Csr[rr].re, n)*xv.x - rdl(Csr[rr].im, n)*xv.y;
            }
        }
        float* outh = out + h * LL;
        #pragma unroll
        for (int rr = 0; rr < 4; ++rr) {
            outh[(4*widu + rr)*64 + j] = 2.0f * accK[rr];
        }
    }
}

extern "C" void kernel_launch(void* const* d_in, const int* in_sizes, int n_in,
                              void* d_out, int out_size, void* d_ws, size_t ws_size,
                              hipStream_t stream) {
    const float* A_real = (const float*)d_in[0];
    const float* A_imag = (const float*)d_in[1];
    const float* B_real = (const float*)d_in[2];
    const float* B_imag = (const float*)d_in[3];
    const float* P_real = (const float*)d_in[4];
    const float* P_imag = (const float*)d_in[5];
    const float* C_real = (const float*)d_in[6];
    const float* C_imag = (const float*)d_in[7];
    const float* log_dt = (const float*)d_in[8];
    float* out = (float*)d_out;

    const size_t lds = 57344 + 128*sizeof(float2);   // 58368 B
    ssm_dplr_kernel<<<256, 512, lds, stream>>>(
        A_real, A_imag, B_real, B_imag, P_real, P_imag,
        C_real, C_imag, log_dt, out);
}